// Round 1
// baseline (544.979 us; speedup 1.0000x reference)
//
#include <hip/hip_runtime.h>
#include <math.h>

// Problem constants (fixed by setup_inputs)
constexpr int B = 16, C = 64, H = 256, W = 256;
constexpr int HW = H * W;            // 65536
constexpr int BHW = B * HW;          // 1048576
constexpr int K = 11, P = 5;         // 11x11 gaussian, pad 5
#define EPS 1e-6f

// ---------------------------------------------------------------------------
// Kernel 1: channel reduction.  For each pixel (b,h,w):
//   sxx = sum_c x^2, sxy = sum_c x*y, syy = sum_c y^2
// Each thread owns 4 consecutive w-pixels (float4 loads, 16B/lane).
// Reads 512 MB (the structural floor of this problem), writes 12 MB.
// ---------------------------------------------------------------------------
__global__ __launch_bounds__(256) void k_reduce(
    const float* __restrict__ x, const float* __restrict__ y,
    float* __restrict__ s /* [3][B][HW] */)
{
    const int GPI = HW / 4;                       // float4 groups per image plane = 16384
    int idx = blockIdx.x * 256 + threadIdx.x;     // [0, B*GPI)
    int b = idx >> 14;                            // idx / GPI
    int g = idx & (GPI - 1);

    const float4* x4 = (const float4*)x + (size_t)b * C * GPI + g;
    const float4* y4 = (const float4*)y + (size_t)b * C * GPI + g;

    float4 axx = make_float4(0.f, 0.f, 0.f, 0.f);
    float4 axy = axx, ayy = axx;

#pragma unroll 8
    for (int c = 0; c < C; ++c) {
        float4 xv = x4[c * GPI];
        float4 yv = y4[c * GPI];
        axx.x += xv.x * xv.x; axx.y += xv.y * xv.y;
        axx.z += xv.z * xv.z; axx.w += xv.w * xv.w;
        axy.x += xv.x * yv.x; axy.y += xv.y * yv.y;
        axy.z += xv.z * yv.z; axy.w += xv.w * yv.w;
        ayy.x += yv.x * yv.x; ayy.y += yv.y * yv.y;
        ayy.z += yv.z * yv.z; ayy.w += yv.w * yv.w;
    }

    float4* s4 = (float4*)s;
    int o = idx;                                   // == b*GPI + g
    s4[o]                 = axx;
    s4[(BHW / 4) + o]     = axy;
    s4[2 * (BHW / 4) + o] = ayy;
}

// ---------------------------------------------------------------------------
// The 11x11 gaussian is rank-1:  g2d[i][j] = (g[5][j]/sqrt(g[5][5])) *
//                                            (g[i][5]/sqrt(g[5][5]))
// so we blur with two 1-D 11-tap passes.
// ---------------------------------------------------------------------------

// Kernel 2: horizontal blur of the 3 maps (zero-padded SAME).
__global__ __launch_bounds__(256) void k_hblur(
    const float* __restrict__ s, const float* __restrict__ gauss,
    float* __restrict__ t /* [3][B][HW] */)
{
    int idx = blockIdx.x * 256 + threadIdx.x;      // [0, BHW)
    int w = idx & (W - 1);
    int rowbase = idx - w;

    float inv = 1.0f / sqrtf(gauss[5 * K + 5]);    // 1/sqrt(center)
    float wt[K];
#pragma unroll
    for (int j = 0; j < K; ++j) wt[j] = gauss[5 * K + j] * inv;  // row 5

    float a0 = 0.f, a1 = 0.f, a2 = 0.f;
#pragma unroll
    for (int j = 0; j < K; ++j) {
        int ww = w + j - P;
        if (ww < 0 || ww >= W) continue;           // zero pad
        float wj = wt[j];
        a0 += wj * s[rowbase + ww];
        a1 += wj * s[BHW + rowbase + ww];
        a2 += wj * s[2 * BHW + rowbase + ww];
    }
    t[idx]           = a0;
    t[BHW + idx]     = a1;
    t[2 * BHW + idx] = a2;
}

// Kernel 3: vertical blur + final cosine combine.
__global__ __launch_bounds__(256) void k_vblur_combine(
    const float* __restrict__ t, const float* __restrict__ gauss,
    float* __restrict__ out /* [B][HW] */)
{
    int idx = blockIdx.x * 256 + threadIdx.x;      // [0, BHW)
    int hw = idx & (HW - 1);
    int h = hw >> 8;                               // / W

    float inv = 1.0f / sqrtf(gauss[5 * K + 5]);
    float wt[K];
#pragma unroll
    for (int i = 0; i < K; ++i) wt[i] = gauss[i * K + 5] * inv;  // col 5

    float axx = 0.f, axy = 0.f, ayy = 0.f;
#pragma unroll
    for (int i = 0; i < K; ++i) {
        int hh = h + i - P;
        if (hh < 0 || hh >= H) continue;           // zero pad
        float wi = wt[i];
        int off = idx + (i - P) * W;
        axx += wi * t[off];
        axy += wi * t[BHW + off];
        ayy += wi * t[2 * BHW + off];
    }
    out[idx] = axy / (sqrtf(axx) * sqrtf(ayy) + EPS);
}

extern "C" void kernel_launch(void* const* d_in, const int* in_sizes, int n_in,
                              void* d_out, int out_size, void* d_ws, size_t ws_size,
                              hipStream_t stream) {
    const float* x     = (const float*)d_in[0];
    const float* y     = (const float*)d_in[1];
    const float* gauss = (const float*)d_in[2];
    float* out = (float*)d_out;

    float* s = (float*)d_ws;        // [3][B][HW]  12 MB
    float* t = s + 3 * BHW;         // [3][B][HW]  12 MB  (24 MB total ws)

    // K1: 16 * 65536 / 4 pixels-groups / 256 threads = 1024 blocks
    k_reduce<<<B * (HW / 4) / 256, 256, 0, stream>>>(x, y, s);
    // K2/K3: 1M pixels / 256 = 4096 blocks
    k_hblur<<<BHW / 256, 256, 0, stream>>>(s, gauss, t);
    k_vblur_combine<<<BHW / 256, 256, 0, stream>>>(t, gauss, out);
}